// Round 1
// baseline (494.322 us; speedup 1.0000x reference)
//
#include <hip/hip_runtime.h>

#define H   488
#define HH  (H*H)        // 238144
#define AW  484          // H - 5 + 1
#define KK  6
#define BB  32
#define NB4 (HH/4)       // 59536, exact

// ---------------- shared device helpers ----------------

// masked load: value is 0 if (i,j) lies inside any of the nr zeroed 5x5 rects
__device__ __forceinline__ float mload(const float* h, int i, int j,
                                       const int* rr, const int* rc, int nr) {
    float v = h[i * H + j];
    for (int t = 0; t < nr; ++t)
        if ((unsigned)(i - rr[t]) < 5u && (unsigned)(j - rc[t]) < 5u) v = 0.0f;
    return v;
}

// wave-collective scan of one window-row r: computes all 484 5x5 window sums
// (f64, exact for 25 f32 addends) and returns (max value, min c on ties) on all lanes.
__device__ __forceinline__ void row_scan(const float* h, int r,
                                         const int* rr, const int* rc, int nr,
                                         double& bestv, int& bestc) {
    int lane = threadIdx.x & 63;
    double bv = -1.0; int bc = 0x7fffffff;
    for (int base = 0; base < AW; base += 64) {
        int j0 = base + lane;
        double csA = 0.0, csB = 0.0;
        if (j0 < H) {
            #pragma unroll
            for (int i = 0; i < 5; ++i) {
                float v = h[(r + i) * H + j0];
                for (int t = 0; t < nr; ++t)
                    if ((unsigned)(r + i - rr[t]) < 5u && (unsigned)(j0 - rc[t]) < 5u) v = 0.0f;
                csA += (double)v;
            }
        }
        int jb = base + 64 + lane;
        if (lane < 4 && jb < H) {
            #pragma unroll
            for (int i = 0; i < 5; ++i) {
                float v = h[(r + i) * H + jb];
                for (int t = 0; t < nr; ++t)
                    if ((unsigned)(r + i - rr[t]) < 5u && (unsigned)(jb - rc[t]) < 5u) v = 0.0f;
                csB += (double)v;
            }
        }
        double s = 0.0;
        #pragma unroll
        for (int k = 0; k < 5; ++k) {
            double vA = __shfl_down(csA, (unsigned)k);
            int srcb = lane + k - 64; if (srcb < 0) srcb = 0;
            double vB = __shfl(csB, srcb);
            s += (lane + k < 64) ? vA : vB;
        }
        int c = base + lane;
        if (c < AW && s > bv) { bv = s; bc = c; }   // ascending c => strict > keeps first
    }
    #pragma unroll
    for (int off = 32; off; off >>= 1) {
        double ov = __shfl_down(bv, (unsigned)off);
        int    oc = __shfl_down(bc, (unsigned)off);
        if (ov > bv || (ov == bv && oc < bc)) { bv = ov; bc = oc; }
    }
    bestv = __shfl(bv, 0);
    bestc = __shfl(bc, 0);
}

// ---------------- kernel A: initial per-row window maxima (wide) ----------------
__global__ __launch_bounds__(256) void kA(const float* __restrict__ hm,
                                          double* __restrict__ rowV, int* __restrict__ rowC) {
    int b   = blockIdx.x & 31;          // batch -> XCD locality (blockIdx % 8 heuristic)
    int grp = blockIdx.x >> 5;          // 0..120
    int wave = threadIdx.x >> 6;        // 4 waves/block
    int r = grp * 4 + wave;             // 121*4 == 484 exact
    const float* h = hm + b * HH;
    double bv; int bc;
    row_scan(h, r, nullptr, nullptr, 0, bv, bc);
    if ((threadIdx.x & 63) == 0) { rowV[b * AW + r] = bv; rowC[b * AW + r] = bc; }
}

// ---------------- kernel B: sequential greedy rect selection (1 block/batch) ----------------
__global__ __launch_bounds__(384) void kB(const float* __restrict__ hm,
                                          const double* __restrict__ rowV, const int* __restrict__ rowC,
                                          int* __restrict__ rectR, int* __restrict__ rectC,
                                          float* __restrict__ maxv, int* __restrict__ scanres) {
    int b = blockIdx.x;
    const float* h = hm + b * HH;
    __shared__ double rv[AW];
    __shared__ int    rcs[AW];
    __shared__ int    rrS[KK], rcS[KK];
    __shared__ int    selR, selC;
    for (int i = threadIdx.x; i < AW; i += 384) { rv[i] = rowV[b * AW + i]; rcs[i] = rowC[b * AW + i]; }
    __syncthreads();
    int wave = threadIdx.x >> 6, lane = threadIdx.x & 63;
    for (int step = 0; step < KK; ++step) {
        if (wave == 0) {   // global argmax over rows: max value, min r on ties
            double bv = -2.0; int br = 0x7fffffff;
            for (int r = lane; r < AW; r += 64) {
                double v = rv[r];
                if (v > bv || (v == bv && r < br)) { bv = v; br = r; }
            }
            #pragma unroll
            for (int off = 32; off; off >>= 1) {
                double ov = __shfl_down(bv, (unsigned)off);
                int    orr = __shfl_down(br, (unsigned)off);
                if (ov > bv || (ov == bv && orr < br)) { bv = ov; br = orr; }
            }
            if (lane == 0) { selR = br; selC = rcs[br]; }
        }
        __syncthreads();
        int R = selR, C = selC;
        if (threadIdx.x == 0) {
            float mv = -1.0f;   // window max over masked values (rects 0..step-1)
            for (int i = 0; i < 5; ++i)
                for (int j = 0; j < 5; ++j) {
                    float v = mload(h, R + i, C + j, rrS, rcS, step);
                    if (v > mv) mv = v;
                }
            maxv[b * KK + step]    = mv;
            rectR[b * KK + step]   = R;
            rectC[b * KK + step]   = C;
            scanres[b * KK + step] = 0x7fffffff;
            rrS[step] = R; rcS[step] = C;   // append rect AFTER computing mv
        }
        __syncthreads();
        if (step < KK - 1) {    // re-scan the <=9 affected window-rows with the new rect
            int lo = R > 4 ? R - 4 : 0, hi = R + 4 < AW ? R + 4 : AW - 1;
            for (int row = lo + wave; row <= hi; row += 6) {
                double bv; int bc;
                row_scan(h, row, rrS, rcS, step + 1, bv, bc);
                if (lane == 0) { rv[row] = bv; rcs[row] = bc; }
            }
        }
        __syncthreads();
    }
}

// ---------------- kernel C: wide first-occurrence equality scans ----------------
__global__ __launch_bounds__(256) void kC(const float* __restrict__ hm,
                                          const int* __restrict__ rectR, const int* __restrict__ rectC,
                                          const float* __restrict__ maxv, int* __restrict__ scanres) {
    int b     = blockIdx.x & 31;
    int rest  = blockIdx.x >> 5;     // 0..95
    int s     = rest % 6;
    int chunk = rest / 6;            // 0..15
    float mv = maxv[b * KK + s];
    int rr[5], rc[5];
    for (int t = 0; t < s; ++t) { rr[t] = rectR[b * KK + t]; rc[t] = rectC[b * KK + t]; }
    const float4* h4 = (const float4*)(hm + b * HH);
    int local = 0x7fffffff;
    for (int i4 = chunk * 256 + threadIdx.x; i4 < NB4; i4 += 4096) {
        float4 v = h4[i4];
        float vs[4] = {v.x, v.y, v.z, v.w};
        #pragma unroll
        for (int e = 0; e < 4; ++e) {
            if (vs[e] == mv) {
                int n = 4 * i4 + e;
                int i = n / H, j = n - i * H;
                bool masked = false;
                for (int t = 0; t < s; ++t)
                    if ((unsigned)(i - rr[t]) < 5u && (unsigned)(j - rc[t]) < 5u) masked = true;
                if (!masked && n < local) local = n;
            }
        }
    }
    __shared__ int sm;
    if (threadIdx.x == 0) sm = 0x7fffffff;
    __syncthreads();
    if (local != 0x7fffffff) atomicMin(&sm, local);
    __syncthreads();
    if (threadIdx.x == 0 && sm != 0x7fffffff) atomicMin(&scanres[b * KK + s], sm);
}

// ---------------- kernel D: refinement + round + confidences (1 block/batch) ----------------
__global__ __launch_bounds__(384) void kD(const float* __restrict__ hm,
                                          const int* __restrict__ scanres, float* __restrict__ out) {
    int b = blockIdx.x;
    const float* h = hm + b * HH;
    __shared__ float cly[2][KK], clx[2][KK];
    if (threadIdx.x < KK) {
        int fh = scanres[b * KK + threadIdx.x];
        cly[0][threadIdx.x] = (float)(fh / H);
        clx[0][threadIdx.x] = (float)(fh % H);
    }
    __syncthreads();
    int wave = threadIdx.x >> 6, lane = threadIdx.x & 63;   // 6 waves = 6 clusters
    int cur = 0;
    for (int it = 0; it < 10; ++it) {
        float ys[KK], xs[KK];
        #pragma unroll
        for (int q = 0; q < KK; ++q) { ys[q] = cly[cur][q]; xs[q] = clx[cur][q]; }
        int k = wave;
        float cy = ys[k], cx = xs[k];
        int fy = (int)floorf(cy), fx = (int)floorf(cx);
        int i0 = fy - 12 > 0 ? fy - 12 : 0, i1 = fy + 13 < H - 1 ? fy + 13 : H - 1;
        int j0 = fx - 12 > 0 ? fx - 12 : 0, j1 = fx + 13 < H - 1 ? fx + 13 : H - 1;
        double sy = 0.0, sx = 0.0, sw = 0.0;
        for (int i = i0; i <= i1; ++i) {
            for (int j = j0 + lane; j <= j1; j += 64) {
                float fi = (float)i, fj = (float)j;
                float dq[KK];
                #pragma unroll
                for (int q = 0; q < KK; ++q) {      // fp32-faithful, no FMA contraction
                    float dy = __fsub_rn(fi, ys[q]);
                    float dx = __fsub_rn(fj, xs[q]);
                    float d2 = __fadd_rn(__fmul_rn(dy, dy), __fmul_rn(dx, dx));
                    float dd = __fsqrt_rn(d2);
                    dq[q] = fmaxf(dd, 0.001f);
                }
                float d = dq[k];
                if (d < 12.0f) {
                    float m = dq[0];
                    #pragma unroll
                    for (int q = 1; q < KK; ++q) m = fminf(m, dq[q]);
                    float hv = h[i * H + j];
                    float w = __fmul_rn(__fdiv_rn(hv, d), __fdiv_rn(m, d));
                    sw += (double)w;
                    sy += (double)w * (double)i;
                    sx += (double)w * (double)j;
                }
            }
        }
        #pragma unroll
        for (int off = 32; off; off >>= 1) {
            sy += __shfl_down(sy, (unsigned)off);
            sx += __shfl_down(sx, (unsigned)off);
            sw += __shfl_down(sw, (unsigned)off);
        }
        if (lane == 0) {
            cly[cur ^ 1][k] = (float)(sy / sw);
            clx[cur ^ 1][k] = (float)(sx / sw);
        }
        __syncthreads();
        cur ^= 1;
    }
    if (threadIdx.x < KK) {
        int k = threadIdx.x;
        int iy = __float2int_rn(cly[cur][k]);   // round-half-even, matches jnp.round
        int ix = __float2int_rn(clx[cur][k]);
        out[b * (KK * 2) + 2 * k]     = (float)iy;
        out[b * (KK * 2) + 2 * k + 1] = (float)ix;
        int s0 = iy - 2; if (s0 < 0) s0 = 0; if (s0 > H - 4) s0 = H - 4;   // clamped dynamic_slice
        int s1 = ix - 2; if (s1 < 0) s1 = 0; if (s1 > H - 4) s1 = H - 4;
        double cs = 0.0;
        for (int i = 0; i < 4; ++i)
            for (int j = 0; j < 4; ++j) cs += (double)h[(s0 + i) * H + (s1 + j)];
        out[BB * KK * 2 + b * KK + k] = (float)cs;
    }
}

// ---------------- launch ----------------
extern "C" void kernel_launch(void* const* d_in, const int* in_sizes, int n_in,
                              void* d_out, int out_size, void* d_ws, size_t ws_size,
                              hipStream_t stream) {
    const float* hm = (const float*)d_in[0];
    float* out = (float*)d_out;

    // workspace layout (doubles first for alignment): ~189 KB total
    double* rowV    = (double*)d_ws;                 // 32*484 f64
    int*    rowC    = (int*)(rowV + BB * AW);        // 32*484 i32
    int*    rectR   = rowC + BB * AW;                // 32*6
    int*    rectC   = rectR + BB * KK;               // 32*6
    float*  maxv    = (float*)(rectC + BB * KK);     // 32*6
    int*    scanres = (int*)(maxv + BB * KK);        // 32*6

    kA<<<BB * 121, 256, 0, stream>>>(hm, rowV, rowC);
    kB<<<BB, 384, 0, stream>>>(hm, rowV, rowC, rectR, rectC, maxv, scanres);
    kC<<<3072, 256, 0, stream>>>(hm, rectR, rectC, maxv, scanres);
    kD<<<BB, 384, 0, stream>>>(hm, scanres, out);
}

// Round 2
// 214.778 us; speedup vs baseline: 2.3016x; 2.3016x over previous
//
#include <hip/hip_runtime.h>

#define H   488
#define HH  (H*H)        // 238144
#define AW  484          // H - 5 + 1
#define KK  6
#define BB  32
#define NB4 (HH/4)       // 59536, exact

// masked load: value is 0 if (i,j) lies inside any of the nr zeroed 5x5 rects
__device__ __forceinline__ float mload(const float* h, int i, int j,
                                       const int* rr, const int* rc, int nr) {
    float v = h[i * H + j];
    for (int t = 0; t < nr; ++t)
        if ((unsigned)(i - rr[t]) < 5u && (unsigned)(j - rc[t]) < 5u) v = 0.0f;
    return v;
}

// ---------------- kernel A: initial per-row window maxima (wide, separable) ----------------
// grid: 32 batches x 121 row-groups (4 window-rows each), 256 threads.
// Association (must match kB): colsum = ((((v0+v1)+v2)+v3)+v4) f64;
// horizontal = ((((c0+c1)+c2)+c3)+c4) f64.
__global__ __launch_bounds__(256) void kA(const float* __restrict__ hm,
                                          double* __restrict__ rowV, int* __restrict__ rowC) {
    int b   = blockIdx.x & 31;          // batch -> XCD locality
    int grp = blockIdx.x >> 5;          // 0..120
    int r0  = grp * 4;                  // first window-row; needs hm rows r0..r0+7
    const float* h = hm + b * HH;
    __shared__ float  stage[8 * H];     // 15.6 KB
    __shared__ double colsum[4 * H];    // 15.6 KB

    // stage 8 contiguous hm rows (one linear float4 copy)
    const float4* g4 = (const float4*)(h + r0 * H);
    float4* st4 = (float4*)stage;
    for (int e = threadIdx.x; e < 8 * H / 4; e += 256) st4[e] = g4[e];
    __syncthreads();

    // vertical 5-sums for 4 window-rows
    for (int e = threadIdx.x; e < 4 * H; e += 256) {
        int rr = e / H, j = e - rr * H;
        double cs = 0.0;
        #pragma unroll
        for (int i = 0; i < 5; ++i) cs += (double)stage[(rr + i) * H + j];
        colsum[e] = cs;
    }
    __syncthreads();

    // horizontal 5-sums + per-row (max, first col) reduce; one wave per window-row
    int wave = threadIdx.x >> 6, lane = threadIdx.x & 63;
    int r = r0 + wave;
    double bv = -1.0; int bc = 0x7fffffff;
    for (int c = lane; c < AW; c += 64) {
        double s = 0.0;
        #pragma unroll
        for (int k = 0; k < 5; ++k) s += colsum[wave * H + c + k];
        if (s > bv || (s == bv && c < bc)) { bv = s; bc = c; }
    }
    #pragma unroll
    for (int off = 32; off; off >>= 1) {
        double ov = __shfl_down(bv, (unsigned)off);
        int    oc = __shfl_down(bc, (unsigned)off);
        if (ov > bv || (ov == bv && oc < bc)) { bv = ov; bc = oc; }
    }
    if (lane == 0) { rowV[b * AW + r] = bv; rowC[b * AW + r] = bc; }
}

// ---------------- kernel B: sequential greedy rect selection (1 block/batch, 1024 thr) ----------------
__global__ __launch_bounds__(1024) void kB(const float* __restrict__ hm,
                                           const double* __restrict__ rowV, const int* __restrict__ rowC,
                                           int* __restrict__ rectR, int* __restrict__ rectC,
                                           float* __restrict__ maxv, int* __restrict__ scanres) {
    int b = blockIdx.x;
    const float* h = hm + b * HH;
    __shared__ double rv[AW];
    __shared__ int    rcs[AW];
    __shared__ double colsum[9 * H];    // 35.1 KB
    __shared__ int    rrS[KK], rcS[KK];
    __shared__ int    selR, selC;
    int tid = threadIdx.x, wave = tid >> 6, lane = tid & 63;

    if (tid < AW) { rv[tid] = rowV[b * AW + tid]; rcs[tid] = rowC[b * AW + tid]; }
    __syncthreads();

    for (int step = 0; step < KK; ++step) {
        if (wave == 0) {
            // argmax over rows: (max value, min r)
            double bv = -2.0; int br = 0x7fffffff;
            for (int r = lane; r < AW; r += 64) {
                double v = rv[r];
                if (v > bv || (v == bv && r < br)) { bv = v; br = r; }
            }
            #pragma unroll
            for (int off = 32; off; off >>= 1) {
                double ov = __shfl_down(bv, (unsigned)off);
                int    orr = __shfl_down(br, (unsigned)off);
                if (ov > bv || (ov == bv && orr < br)) { bv = ov; br = orr; }
            }
            int R = __shfl(br, 0);
            int C = rcs[R];             // same-address LDS read: broadcast
            // 5x5 window max over masked values (rects 0..step-1), 25 lanes
            float wv = -1.0f;
            if (lane < 25) wv = mload(h, R + lane / 5, C + lane % 5, rrS, rcS, step);
            #pragma unroll
            for (int off = 32; off; off >>= 1) {
                float o = __shfl_down(wv, (unsigned)off);
                wv = fmaxf(wv, o);
            }
            if (lane == 0) {
                maxv[b * KK + step]    = wv;
                rectR[b * KK + step]   = R;
                rectC[b * KK + step]   = C;
                scanres[b * KK + step] = 0x7fffffff;
                rrS[step] = R; rcS[step] = C;
                selR = R; selC = C;
            }
        }
        __syncthreads();
        if (step == KK - 1) break;

        int R = selR, C = selC;
        int lo = R > 4 ? R - 4 : 0, hi = R + 4 < AW ? R + 4 : AW - 1;
        int nrows = hi - lo + 1;
        // phase 4a: masked vertical 5-sums for affected window-rows (rects 0..step)
        for (int e = tid; e < nrows * H; e += 1024) {
            int rr = e / H, j = e - rr * H;
            int wrow = lo + rr;
            double cs = 0.0;
            #pragma unroll
            for (int i = 0; i < 5; ++i) {
                float v = h[(wrow + i) * H + j];
                for (int t = 0; t <= step; ++t)
                    if ((unsigned)(wrow + i - rrS[t]) < 5u && (unsigned)(j - rcS[t]) < 5u) v = 0.0f;
                cs += (double)v;
            }
            colsum[e] = cs;
        }
        __syncthreads();
        // phase 4b: horizontal 5-sums + per-row reduce; one wave per affected row
        if (wave < nrows) {
            int row = lo + wave;
            double bv = -1.0; int bc = 0x7fffffff;
            for (int c = lane; c < AW; c += 64) {
                double s = 0.0;
                #pragma unroll
                for (int k = 0; k < 5; ++k) s += colsum[wave * H + c + k];
                if (s > bv || (s == bv && c < bc)) { bv = s; bc = c; }
            }
            #pragma unroll
            for (int off = 32; off; off >>= 1) {
                double ov = __shfl_down(bv, (unsigned)off);
                int    oc = __shfl_down(bc, (unsigned)off);
                if (ov > bv || (ov == bv && oc < bc)) { bv = ov; bc = oc; }
            }
            if (lane == 0) { rv[row] = bv; rcs[row] = bc; }
        }
        __syncthreads();
    }
}

// ---------------- kernel C: fused first-occurrence equality scans (one pass, 6 steps) ----------------
__global__ __launch_bounds__(256) void kC(const float* __restrict__ hm,
                                          const int* __restrict__ rectR, const int* __restrict__ rectC,
                                          const float* __restrict__ maxv, int* __restrict__ scanres) {
    int b     = blockIdx.x & 31;
    int chunk = blockIdx.x >> 5;     // 0..15
    float mv[KK];
    int rr[5], rc[5];
    #pragma unroll
    for (int s = 0; s < KK; ++s) mv[s] = maxv[b * KK + s];
    #pragma unroll
    for (int t = 0; t < 5; ++t) { rr[t] = rectR[b * KK + t]; rc[t] = rectC[b * KK + t]; }
    const float4* h4 = (const float4*)(hm + b * HH);
    int local[KK];
    #pragma unroll
    for (int s = 0; s < KK; ++s) local[s] = 0x7fffffff;
    for (int i4 = chunk * 256 + threadIdx.x; i4 < NB4; i4 += 4096) {
        float4 v = h4[i4];
        float vs[4] = {v.x, v.y, v.z, v.w};
        #pragma unroll
        for (int e = 0; e < 4; ++e) {
            #pragma unroll
            for (int s = 0; s < KK; ++s) {
                if (vs[e] == mv[s]) {
                    int n = 4 * i4 + e;
                    int i = n / H, j = n - i * H;
                    bool masked = false;
                    for (int t = 0; t < s; ++t)
                        if ((unsigned)(i - rr[t]) < 5u && (unsigned)(j - rc[t]) < 5u) masked = true;
                    if (!masked && n < local[s]) local[s] = n;
                }
            }
        }
    }
    __shared__ int sm[KK];
    if (threadIdx.x < KK) sm[threadIdx.x] = 0x7fffffff;
    __syncthreads();
    #pragma unroll
    for (int s = 0; s < KK; ++s)
        if (local[s] != 0x7fffffff) atomicMin(&sm[s], local[s]);
    __syncthreads();
    if (threadIdx.x < KK && sm[threadIdx.x] != 0x7fffffff)
        atomicMin(&scanres[b * KK + threadIdx.x], sm[threadIdx.x]);
}

// ---------------- kernel D: refinement + round + confidences (1 block/batch) ----------------
__global__ __launch_bounds__(384) void kD(const float* __restrict__ hm,
                                          const int* __restrict__ scanres, float* __restrict__ out) {
    int b = blockIdx.x;
    const float* h = hm + b * HH;
    __shared__ float cly[2][KK], clx[2][KK];
    if (threadIdx.x < KK) {
        int fh = scanres[b * KK + threadIdx.x];
        cly[0][threadIdx.x] = (float)(fh / H);
        clx[0][threadIdx.x] = (float)(fh % H);
    }
    __syncthreads();
    int wave = threadIdx.x >> 6, lane = threadIdx.x & 63;   // 6 waves = 6 clusters
    int cur = 0;
    for (int it = 0; it < 10; ++it) {
        float ys[KK], xs[KK];
        #pragma unroll
        for (int q = 0; q < KK; ++q) { ys[q] = cly[cur][q]; xs[q] = clx[cur][q]; }
        int k = wave;
        float cy = ys[k], cx = xs[k];
        int fy = (int)floorf(cy), fx = (int)floorf(cx);
        int i0 = fy - 12 > 0 ? fy - 12 : 0, i1 = fy + 13 < H - 1 ? fy + 13 : H - 1;
        int j0 = fx - 12 > 0 ? fx - 12 : 0, j1 = fx + 13 < H - 1 ? fx + 13 : H - 1;
        int NI = i1 - i0 + 1, NJ = j1 - j0 + 1, NT = NI * NJ;
        double sy = 0.0, sx = 0.0, sw = 0.0;
        for (int idx = lane; idx < NT; idx += 64) {
            int di = idx / NJ, dj = idx - di * NJ;
            int i = i0 + di, j = j0 + dj;
            float fi = (float)i, fj = (float)j;
            float dq[KK];
            #pragma unroll
            for (int q = 0; q < KK; ++q) {      // fp32-faithful, no FMA contraction
                float dy = __fsub_rn(fi, ys[q]);
                float dx = __fsub_rn(fj, xs[q]);
                float d2 = __fadd_rn(__fmul_rn(dy, dy), __fmul_rn(dx, dx));
                float dd = __fsqrt_rn(d2);
                dq[q] = fmaxf(dd, 0.001f);
            }
            float d = dq[k];
            if (d < 12.0f) {
                float m = dq[0];
                #pragma unroll
                for (int q = 1; q < KK; ++q) m = fminf(m, dq[q]);
                float hv = h[i * H + j];
                float w = __fmul_rn(__fdiv_rn(hv, d), __fdiv_rn(m, d));
                sw += (double)w;
                sy += (double)w * (double)i;
                sx += (double)w * (double)j;
            }
        }
        #pragma unroll
        for (int off = 32; off; off >>= 1) {
            sy += __shfl_down(sy, (unsigned)off);
            sx += __shfl_down(sx, (unsigned)off);
            sw += __shfl_down(sw, (unsigned)off);
        }
        if (lane == 0) {
            cly[cur ^ 1][k] = (float)(sy / sw);
            clx[cur ^ 1][k] = (float)(sx / sw);
        }
        __syncthreads();
        cur ^= 1;
    }
    if (threadIdx.x < KK) {
        int k = threadIdx.x;
        int iy = __float2int_rn(cly[cur][k]);   // round-half-even, matches jnp.round
        int ix = __float2int_rn(clx[cur][k]);
        out[b * (KK * 2) + 2 * k]     = (float)iy;
        out[b * (KK * 2) + 2 * k + 1] = (float)ix;
        int s0 = iy - 2; if (s0 < 0) s0 = 0; if (s0 > H - 4) s0 = H - 4;   // clamped dynamic_slice
        int s1 = ix - 2; if (s1 < 0) s1 = 0; if (s1 > H - 4) s1 = H - 4;
        double cs = 0.0;
        for (int i = 0; i < 4; ++i)
            for (int j = 0; j < 4; ++j) cs += (double)h[(s0 + i) * H + (s1 + j)];
        out[BB * KK * 2 + b * KK + k] = (float)cs;
    }
}

// ---------------- launch ----------------
extern "C" void kernel_launch(void* const* d_in, const int* in_sizes, int n_in,
                              void* d_out, int out_size, void* d_ws, size_t ws_size,
                              hipStream_t stream) {
    const float* hm = (const float*)d_in[0];
    float* out = (float*)d_out;

    double* rowV    = (double*)d_ws;                 // 32*484 f64
    int*    rowC    = (int*)(rowV + BB * AW);        // 32*484 i32
    int*    rectR   = rowC + BB * AW;                // 32*6
    int*    rectC   = rectR + BB * KK;               // 32*6
    float*  maxv    = (float*)(rectC + BB * KK);     // 32*6
    int*    scanres = (int*)(maxv + BB * KK);        // 32*6

    kA<<<BB * 121, 256, 0, stream>>>(hm, rowV, rowC);
    kB<<<BB, 1024, 0, stream>>>(hm, rowV, rowC, rectR, rectC, maxv, scanres);
    kC<<<BB * 16, 256, 0, stream>>>(hm, rectR, rectC, maxv, scanres);
    kD<<<BB, 384, 0, stream>>>(hm, scanres, out);
}

// Round 3
// 199.378 us; speedup vs baseline: 2.4793x; 1.0772x over previous
//
#include <hip/hip_runtime.h>

#define H   488
#define HH  (H*H)        // 238144
#define AW  484          // H - 5 + 1
#define KK  6
#define BB  32
#define NB4 (HH/4)       // 59536, exact

// masked load: value is 0 if (i,j) lies inside any of the nr zeroed 5x5 rects
__device__ __forceinline__ float mload(const float* h, int i, int j,
                                       const int* rr, const int* rc, int nr) {
    float v = h[i * H + j];
    for (int t = 0; t < nr; ++t)
        if ((unsigned)(i - rr[t]) < 5u && (unsigned)(j - rc[t]) < 5u) v = 0.0f;
    return v;
}

// ---------------- kernel A: per-row per-64col-block window maxima ----------------
// grid: 32 batches x 61 groups (8 window-rows each), 512 threads.
// Association (must match kB): colsum = ((((v0+v1)+v2)+v3)+v4) f64;
// horizontal = ((((c0+c1)+c2)+c3)+c4) f64.
__global__ __launch_bounds__(512) void kA(const float* __restrict__ hm,
                                          double* __restrict__ blockV, int* __restrict__ blockC) {
    int b  = blockIdx.x & 31;           // batch -> XCD locality
    int g  = blockIdx.x >> 5;           // 0..60
    int r0 = g * 8;
    int nw    = (r0 + 8 <= AW) ? 8 : (AW - r0);   // window-rows this block
    int nrows = (r0 + 12 <= H) ? 12 : (H - r0);   // hm rows staged
    const float* h = hm + b * HH;
    __shared__ float  stage[12 * H];    // 23.4 KB
    __shared__ double colsum[8][H];     // 31.2 KB

    const float4* g4 = (const float4*)(h + r0 * H);
    float4* s4 = (float4*)stage;
    int n4 = nrows * (H / 4);
    for (int e = threadIdx.x; e < n4; e += 512) s4[e] = g4[e];
    __syncthreads();

    int tot = nw * H;
    for (int e = threadIdx.x; e < tot; e += 512) {
        int w = e / H, j = e - w * H;
        double cs = 0.0;
        #pragma unroll
        for (int i = 0; i < 5; ++i) cs += (double)stage[(w + i) * H + j];
        colsum[w][j] = cs;
    }
    __syncthreads();

    int wave = threadIdx.x >> 6, lane = threadIdx.x & 63;
    if (wave < nw) {
        int r = r0 + wave;
        for (int p = 0; p < 8; ++p) {
            int c = p * 64 + lane;
            double bv = -1.0; int bc = 0x7fffffff;
            if (c < AW) {
                double s = 0.0;
                #pragma unroll
                for (int k = 0; k < 5; ++k) s += colsum[wave][c + k];
                bv = s; bc = c;
            }
            #pragma unroll
            for (int off = 32; off; off >>= 1) {
                double ov = __shfl_down(bv, (unsigned)off);
                int    oc = __shfl_down(bc, (unsigned)off);
                if (ov > bv || (ov == bv && oc < bc)) { bv = ov; bc = oc; }
            }
            if (lane == 0) {
                blockV[(b * AW + r) * 8 + p] = bv;
                blockC[(b * AW + r) * 8 + p] = bc;
            }
        }
    }
}

// ---------------- kernel B: greedy selection w/ incremental block maxima ----------------
__global__ __launch_bounds__(1024) void kB(const float* __restrict__ hm,
                                           const double* __restrict__ blockV, const int* __restrict__ blockC,
                                           int* __restrict__ rectR, int* __restrict__ rectC,
                                           float* __restrict__ maxv, int* __restrict__ scanres) {
    int b = blockIdx.x;
    const float* h = hm + b * HH;
    __shared__ double bV[AW * 8];       // 31.0 KB
    __shared__ int    bC[AW * 8];       // 15.5 KB
    __shared__ double rv[AW];
    __shared__ int    rcs[AW];
    __shared__ int    rrS[KK], rcS[KK];
    __shared__ int    selR, selC, ndirty;
    __shared__ int    dlist[18 * 2];
    int tid = threadIdx.x, wave = tid >> 6, lane = tid & 63;

    for (int e = tid; e < AW * 8; e += 1024) {
        bV[e] = blockV[b * AW * 8 + e];
        bC[e] = blockC[b * AW * 8 + e];
    }
    __syncthreads();
    if (tid < AW) {     // row max = ascending scan of 8 blocks, strict > keeps first col
        double mv = -2.0; int mc = 0x7fffffff;
        for (int p = 0; p < 8; ++p) {
            double v = bV[tid * 8 + p];
            if (v > mv) { mv = v; mc = bC[tid * 8 + p]; }
        }
        rv[tid] = mv; rcs[tid] = mc;
    }
    __syncthreads();

    for (int step = 0; step < KK; ++step) {
        if (wave == 0) {
            double bv = -3.0; int br = 0x7fffffff;
            for (int r = lane; r < AW; r += 64) {
                double v = rv[r];
                if (v > bv || (v == bv && r < br)) { bv = v; br = r; }
            }
            #pragma unroll
            for (int off = 32; off; off >>= 1) {
                double ov = __shfl_down(bv, (unsigned)off);
                int    orr = __shfl_down(br, (unsigned)off);
                if (ov > bv || (ov == bv && orr < br)) { bv = ov; br = orr; }
            }
            int R = __shfl(br, 0);
            int C = rcs[R];
            float wv = -1.0f;   // 5x5 window max over pre-zeroing state (rects 0..step-1)
            if (lane < 25) wv = mload(h, R + lane / 5, C + lane % 5, rrS, rcS, step);
            #pragma unroll
            for (int off = 32; off; off >>= 1) wv = fmaxf(wv, __shfl_down(wv, (unsigned)off));
            if (lane == 0) {
                maxv[b * KK + step]    = wv;
                rectR[b * KK + step]   = R;
                rectC[b * KK + step]   = C;
                scanres[b * KK + step] = 0x7fffffff;
                rrS[step] = R; rcS[step] = C;
                selR = R; selC = C;
                // dirty list: blocks intersecting cols [C-4,C+4] whose argmax lies in it
                int rlo = R > 4 ? R - 4 : 0, rhi = R + 4 < AW ? R + 4 : AW - 1;
                int cb0 = (C > 4 ? C - 4 : 0) >> 6;
                int cb1 = ((C + 4 < AW ? C + 4 : AW - 1)) >> 6;
                int nd = 0;
                for (int r = rlo; r <= rhi; ++r)
                    for (int blk = cb0; blk <= cb1; ++blk) {
                        int ac = bC[r * 8 + blk];
                        if (ac >= C - 4 && ac <= C + 4) { dlist[2 * nd] = r; dlist[2 * nd + 1] = blk; ++nd; }
                    }
                ndirty = nd;
            }
        }
        __syncthreads();
        if (step == KK - 1) break;

        int C = selC;
        // recompute dirty blocks (rects 0..step now active), one wave per unit
        for (int u = wave; u < ndirty; u += 16) {
            int r = dlist[2 * u], blk = dlist[2 * u + 1];
            int jbase = blk * 64;
            // masked colsums: csA at j=jbase+lane, csB at j=jbase+64+lane (lane<4)
            double csA = 0.0, csB = 0.0;
            int jA = jbase + lane;
            if (jA < H) {
                #pragma unroll
                for (int i = 0; i < 5; ++i) csA += (double)mload(h, r + i, jA, rrS, rcS, step + 1);
            }
            int jB = jbase + 64 + lane;
            if (lane < 4 && jB < H) {
                #pragma unroll
                for (int i = 0; i < 5; ++i) csB += (double)mload(h, r + i, jB, rrS, rcS, step + 1);
            }
            double s = 0.0;
            #pragma unroll
            for (int k = 0; k < 5; ++k) {
                double vA = __shfl_down(csA, (unsigned)k);
                int srcb = lane + k - 64; if (srcb < 0) srcb = 0;
                double vB = __shfl(csB, srcb);
                s += (lane + k < 64) ? vA : vB;
            }
            int c = jbase + lane;
            double bv = -1.0; int bc = 0x7fffffff;
            if (c < AW) { bv = s; bc = c; }
            #pragma unroll
            for (int off = 32; off; off >>= 1) {
                double ov = __shfl_down(bv, (unsigned)off);
                int    oc = __shfl_down(bc, (unsigned)off);
                if (ov > bv || (ov == bv && oc < bc)) { bv = ov; bc = oc; }
            }
            if (lane == 0) { bV[r * 8 + blk] = bv; bC[r * 8 + blk] = bc; }
        }
        __syncthreads();
        {   // refresh row maxima for the affected rows
            int R = selR;
            int rlo = R > 4 ? R - 4 : 0, rhi = R + 4 < AW ? R + 4 : AW - 1;
            int t = tid;
            if (t <= rhi - rlo) {
                int r = rlo + t;
                double mv = -2.0; int mc = 0x7fffffff;
                for (int p = 0; p < 8; ++p) {
                    double v = bV[r * 8 + p];
                    if (v > mv) { mv = v; mc = bC[r * 8 + p]; }
                }
                rv[r] = mv; rcs[r] = mc;
            }
        }
        __syncthreads();
        (void)C;
    }
}

// ---------------- kernel C: fused first-occurrence equality scans ----------------
__global__ __launch_bounds__(256) void kC(const float* __restrict__ hm,
                                          const int* __restrict__ rectR, const int* __restrict__ rectC,
                                          const float* __restrict__ maxv, int* __restrict__ scanres) {
    int b     = blockIdx.x & 31;
    int chunk = blockIdx.x >> 5;     // 0..31
    float mv[KK];
    int rr[5], rc[5];
    #pragma unroll
    for (int s = 0; s < KK; ++s) mv[s] = maxv[b * KK + s];
    #pragma unroll
    for (int t = 0; t < 5; ++t) { rr[t] = rectR[b * KK + t]; rc[t] = rectC[b * KK + t]; }
    const float4* h4 = (const float4*)(hm + b * HH);
    int local[KK];
    #pragma unroll
    for (int s = 0; s < KK; ++s) local[s] = 0x7fffffff;
    for (int i4 = chunk * 256 + threadIdx.x; i4 < NB4; i4 += 8192) {
        float4 v = h4[i4];
        float vs[4] = {v.x, v.y, v.z, v.w};
        #pragma unroll
        for (int e = 0; e < 4; ++e) {
            #pragma unroll
            for (int s = 0; s < KK; ++s) {
                if (vs[e] == mv[s]) {
                    int n = 4 * i4 + e;
                    int i = n / H, j = n - i * H;
                    bool masked = false;
                    for (int t = 0; t < s; ++t)
                        if ((unsigned)(i - rr[t]) < 5u && (unsigned)(j - rc[t]) < 5u) masked = true;
                    if (!masked && n < local[s]) local[s] = n;
                }
            }
        }
    }
    __shared__ int sm[KK];
    if (threadIdx.x < KK) sm[threadIdx.x] = 0x7fffffff;
    __syncthreads();
    #pragma unroll
    for (int s = 0; s < KK; ++s)
        if (local[s] != 0x7fffffff) atomicMin(&sm[s], local[s]);
    __syncthreads();
    if (threadIdx.x < KK && sm[threadIdx.x] != 0x7fffffff)
        atomicMin(&scanres[b * KK + threadIdx.x], sm[threadIdx.x]);
}

// ---------------- kernel D: refinement + round + confidences (768 thr, 2 waves/cluster) ----------------
__global__ __launch_bounds__(768) void kD(const float* __restrict__ hm,
                                          const int* __restrict__ scanres, float* __restrict__ out) {
    int b = blockIdx.x;
    const float* h = hm + b * HH;
    __shared__ float  cly[2][KK], clx[2][KK];
    __shared__ double part[KK][2][3];
    if (threadIdx.x < KK) {
        int fh = scanres[b * KK + threadIdx.x];
        cly[0][threadIdx.x] = (float)(fh / H);
        clx[0][threadIdx.x] = (float)(fh % H);
    }
    __syncthreads();
    int wave = threadIdx.x >> 6, lane = threadIdx.x & 63;
    int k = wave >> 1, half = wave & 1;
    int cur = 0;
    for (int it = 0; it < 10; ++it) {
        float ys[KK], xs[KK];
        #pragma unroll
        for (int q = 0; q < KK; ++q) { ys[q] = cly[cur][q]; xs[q] = clx[cur][q]; }
        float cy = ys[k], cx = xs[k];
        int fy = (int)floorf(cy), fx = (int)floorf(cx);
        int i0 = fy - 12 > 0 ? fy - 12 : 0, i1 = fy + 13 < H - 1 ? fy + 13 : H - 1;
        int j0 = fx - 12 > 0 ? fx - 12 : 0, j1 = fx + 13 < H - 1 ? fx + 13 : H - 1;
        double sy = 0.0, sx = 0.0, sw = 0.0;
        for (int idx = half * 64 + lane; idx < 676; idx += 128) {
            int di = idx / 26, dj = idx - di * 26;     // compile-time divisor
            int i = i0 + di, j = j0 + dj;
            if (i <= i1 && j <= j1) {
                float fi = (float)i, fj = (float)j;
                float d2[KK];
                #pragma unroll
                for (int q = 0; q < KK; ++q) {         // fp32-faithful, no FMA contraction
                    float dy = __fsub_rn(fi, ys[q]);
                    float dx = __fsub_rn(fj, xs[q]);
                    d2[q] = __fadd_rn(__fmul_rn(dy, dy), __fmul_rn(dx, dx));
                }
                if (d2[k] < 144.0f) {                  // == (d < 12), exact by monotonicity
                    float m2 = d2[0];
                    #pragma unroll
                    for (int q = 1; q < KK; ++q) m2 = fminf(m2, d2[q]);
                    float d = fmaxf(__fsqrt_rn(d2[k]), 0.001f);
                    float m = fmaxf(__fsqrt_rn(m2), 0.001f);   // == min_q max(sqrt(d2q),.001)
                    float hv = h[i * H + j];
                    float w = __fmul_rn(__fdiv_rn(hv, d), __fdiv_rn(m, d));
                    sw += (double)w;
                    sy += (double)w * (double)i;
                    sx += (double)w * (double)j;
                }
            }
        }
        #pragma unroll
        for (int off = 32; off; off >>= 1) {
            sy += __shfl_down(sy, (unsigned)off);
            sx += __shfl_down(sx, (unsigned)off);
            sw += __shfl_down(sw, (unsigned)off);
        }
        if (lane == 0) { part[k][half][0] = sy; part[k][half][1] = sx; part[k][half][2] = sw; }
        __syncthreads();
        if (threadIdx.x < KK) {
            int q = threadIdx.x;
            double ty = part[q][0][0] + part[q][1][0];
            double tx = part[q][0][1] + part[q][1][1];
            double tw = part[q][0][2] + part[q][1][2];
            cly[cur ^ 1][q] = (float)(ty / tw);
            clx[cur ^ 1][q] = (float)(tx / tw);
        }
        __syncthreads();
        cur ^= 1;
    }
    if (threadIdx.x < KK) {
        int q = threadIdx.x;
        int iy = __float2int_rn(cly[cur][q]);   // round-half-even, matches jnp.round
        int ix = __float2int_rn(clx[cur][q]);
        out[b * (KK * 2) + 2 * q]     = (float)iy;
        out[b * (KK * 2) + 2 * q + 1] = (float)ix;
        int s0 = iy - 2; if (s0 < 0) s0 = 0; if (s0 > H - 4) s0 = H - 4;   // clamped dynamic_slice
        int s1 = ix - 2; if (s1 < 0) s1 = 0; if (s1 > H - 4) s1 = H - 4;
        double cs = 0.0;
        for (int i = 0; i < 4; ++i)
            for (int j = 0; j < 4; ++j) cs += (double)h[(s0 + i) * H + (s1 + j)];
        out[BB * KK * 2 + b * KK + q] = (float)cs;
    }
}

// ---------------- launch ----------------
extern "C" void kernel_launch(void* const* d_in, const int* in_sizes, int n_in,
                              void* d_out, int out_size, void* d_ws, size_t ws_size,
                              hipStream_t stream) {
    const float* hm = (const float*)d_in[0];
    float* out = (float*)d_out;

    // workspace: ~1.5 MB
    double* blockV  = (double*)d_ws;                 // 32*484*8 f64
    int*    blockC  = (int*)(blockV + BB * AW * 8);  // 32*484*8 i32
    int*    rectR   = blockC + BB * AW * 8;          // 32*6
    int*    rectC   = rectR + BB * KK;               // 32*6
    float*  maxv    = (float*)(rectC + BB * KK);     // 32*6
    int*    scanres = (int*)(maxv + BB * KK);        // 32*6

    kA<<<BB * 61, 512, 0, stream>>>(hm, blockV, blockC);
    kB<<<BB, 1024, 0, stream>>>(hm, blockV, blockC, rectR, rectC, maxv, scanres);
    kC<<<BB * 32, 256, 0, stream>>>(hm, rectR, rectC, maxv, scanres);
    kD<<<BB, 768, 0, stream>>>(hm, scanres, out);
}

// Round 4
// 182.969 us; speedup vs baseline: 2.7017x; 1.0897x over previous
//
#include <hip/hip_runtime.h>

#define H   488
#define HH  (H*H)        // 238144
#define AW  484          // H - 5 + 1
#define KK  6
#define BB  32
#define NB4 (HH/4)       // 59536, exact

// masked load: value is 0 if (i,j) lies inside any of the nr zeroed 5x5 rects
__device__ __forceinline__ float mload(const float* h, int i, int j,
                                       const int* rr, const int* rc, int nr) {
    float v = h[i * H + j];
    for (int t = 0; t < nr; ++t)
        if ((unsigned)(i - rr[t]) < 5u && (unsigned)(j - rc[t]) < 5u) v = 0.0f;
    return v;
}

// ---------------- kernel A: per-row per-64col-block window maxima ----------------
// grid: 32 batches x 61 groups (8 window-rows each), 512 threads.
// Association (must match kB): colsum = ((((v0+v1)+v2)+v3)+v4) f64;
// horizontal = ((((c0+c1)+c2)+c3)+c4) f64.
// Layout (transposed for kB): blockV[(b*8 + p)*AW + r].
__global__ __launch_bounds__(512) void kA(const float* __restrict__ hm,
                                          double* __restrict__ blockV, int* __restrict__ blockC) {
    int b  = blockIdx.x & 31;           // batch -> XCD locality
    int g  = blockIdx.x >> 5;           // 0..60
    int r0 = g * 8;
    int nw = (r0 + 8 <= AW) ? 8 : (AW - r0);   // window-rows this block
    const float* h = hm + b * HH;
    __shared__ double colsum[8][H];     // 31.2 KB

    int j = threadIdx.x;
    if (j < H) {
        float v[12];
        #pragma unroll
        for (int i = 0; i < 12; ++i) {
            int row = r0 + i;
            v[i] = (row < H) ? h[row * H + j] : 0.0f;   // 12 independent coalesced loads
        }
        #pragma unroll
        for (int w = 0; w < 8; ++w) {
            double cs = 0.0;
            #pragma unroll
            for (int i = 0; i < 5; ++i) cs += (double)v[w + i];
            colsum[w][j] = cs;
        }
    }
    __syncthreads();

    int wave = threadIdx.x >> 6, lane = threadIdx.x & 63;
    if (wave < nw) {
        int r = r0 + wave;
        for (int p = 0; p < 8; ++p) {
            int c = p * 64 + lane;
            double bv = -1.0; int bc = 0x7fffffff;
            if (c < AW) {
                double s = 0.0;
                #pragma unroll
                for (int k = 0; k < 5; ++k) s += colsum[wave][c + k];
                bv = s; bc = c;
            }
            #pragma unroll
            for (int off = 32; off; off >>= 1) {
                double ov = __shfl_down(bv, (unsigned)off);
                int    oc = __shfl_down(bc, (unsigned)off);
                if (ov > bv || (ov == bv && oc < bc)) { bv = ov; bc = oc; }
            }
            if (lane == 0) {
                blockV[(b * 8 + p) * AW + r] = bv;
                blockC[(b * 8 + p) * AW + r] = bc;
            }
        }
    }
}

// ---------------- kernel B: greedy selection w/ incremental block maxima ----------------
__global__ __launch_bounds__(1024) void kB(const float* __restrict__ hm,
                                           const double* __restrict__ blockV, const int* __restrict__ blockC,
                                           int* __restrict__ rectR, int* __restrict__ rectC,
                                           float* __restrict__ maxv, int* __restrict__ scanres) {
    int b = blockIdx.x;
    const float* h = hm + b * HH;
    __shared__ double bV[8 * AW];       // bV[p*AW + r] -- conflict-free layout
    __shared__ int    bC[8 * AW];
    __shared__ double rv[AW];
    __shared__ int    rcs[AW];
    __shared__ int    rrS[KK], rcS[KK];
    __shared__ int    selR, selC, ndirty;
    __shared__ int    dlist[18 * 2];
    int tid = threadIdx.x, wave = tid >> 6, lane = tid & 63;

    for (int e = tid; e < 8 * AW; e += 1024) {
        bV[e] = blockV[b * 8 * AW + e];
        bC[e] = blockC[b * 8 * AW + e];
    }
    __syncthreads();
    if (tid < AW) {     // row max: ascending p, strict > keeps smallest col on exact ties
        double mv = -2.0; int mc = 0x7fffffff;
        #pragma unroll
        for (int p = 0; p < 8; ++p) {
            double v = bV[p * AW + tid];           // consecutive tid -> consecutive doubles
            if (v > mv) { mv = v; mc = bC[p * AW + tid]; }
        }
        rv[tid] = mv; rcs[tid] = mc;
    }
    __syncthreads();

    for (int step = 0; step < KK; ++step) {
        if (wave == 0) {
            // global argmax over rows: (max value, min r)
            double bv = -3.0; int br = 0x7fffffff;
            for (int r = lane; r < AW; r += 64) {
                double v = rv[r];
                if (v > bv || (v == bv && r < br)) { bv = v; br = r; }
            }
            #pragma unroll
            for (int off = 32; off; off >>= 1) {
                double ov = __shfl_down(bv, (unsigned)off);
                int    orr = __shfl_down(br, (unsigned)off);
                if (ov > bv || (ov == bv && orr < br)) { bv = ov; br = orr; }
            }
            int R = __shfl(br, 0);
            int C = rcs[R];                        // same-address broadcast
            // 5x5 window max over pre-zeroing state (rects 0..step-1): issue loads early
            float wv = -1.0f;
            if (lane < 25) wv = mload(h, R + lane / 5, C + lane % 5, rrS, rcS, step);
            // lane-parallel dirty-list build (overlaps with window-max load latency)
            int rlo = R > 4 ? R - 4 : 0, rhi = R + 4 < AW ? R + 4 : AW - 1;
            int cb0 = (C > 4 ? C - 4 : 0) >> 6;
            int cb1 = (C + 4 < AW ? C + 4 : AW - 1) >> 6;
            int nr = rhi - rlo + 1, nb = cb1 - cb0 + 1;     // <=9 x <=2
            bool pred = false; int dr = 0, db = 0;
            if (lane < nr * nb) {
                if (nb == 2) { dr = rlo + (lane >> 1); db = cb0 + (lane & 1); }
                else         { dr = rlo + lane;        db = cb0; }
                int ac = bC[db * AW + dr];
                pred = (ac >= C - 4 && ac <= C + 4);
            }
            unsigned long long m = __ballot(pred);
            if (pred) {
                int pos = __popcll(m & ((1ull << lane) - 1ull));
                dlist[2 * pos] = dr; dlist[2 * pos + 1] = db;
            }
            #pragma unroll
            for (int off = 32; off; off >>= 1) wv = fmaxf(wv, __shfl_down(wv, (unsigned)off));
            if (lane == 0) {
                ndirty = __popcll(m);
                maxv[b * KK + step]    = wv;
                rectR[b * KK + step]   = R;
                rectC[b * KK + step]   = C;
                scanres[b * KK + step] = 0x7fffffff;
                rrS[step] = R; rcS[step] = C;
                selR = R; selC = C;
            }
        }
        __syncthreads();
        if (step == KK - 1) break;

        // recompute dirty 64-col blocks (rects 0..step active), one wave per unit
        for (int u = wave; u < ndirty; u += 16) {
            int r = dlist[2 * u], blk = dlist[2 * u + 1];
            int jbase = blk * 64;
            double csA = 0.0, csB = 0.0;
            int jA = jbase + lane;
            if (jA < H) {
                #pragma unroll
                for (int i = 0; i < 5; ++i) csA += (double)mload(h, r + i, jA, rrS, rcS, step + 1);
            }
            int jB = jbase + 64 + lane;
            if (lane < 4 && jB < H) {
                #pragma unroll
                for (int i = 0; i < 5; ++i) csB += (double)mload(h, r + i, jB, rrS, rcS, step + 1);
            }
            double s = 0.0;
            #pragma unroll
            for (int k = 0; k < 5; ++k) {
                double vA = __shfl_down(csA, (unsigned)k);
                int srcb = lane + k - 64; if (srcb < 0) srcb = 0;
                double vB = __shfl(csB, srcb);
                s += (lane + k < 64) ? vA : vB;
            }
            int c = jbase + lane;
            double bv = -1.0; int bc = 0x7fffffff;
            if (c < AW) { bv = s; bc = c; }
            #pragma unroll
            for (int off = 32; off; off >>= 1) {
                double ov = __shfl_down(bv, (unsigned)off);
                int    oc = __shfl_down(bc, (unsigned)off);
                if (ov > bv || (ov == bv && oc < bc)) { bv = ov; bc = oc; }
            }
            if (lane == 0) { bV[blk * AW + r] = bv; bC[blk * AW + r] = bc; }
        }
        __syncthreads();
        {   // refresh row maxima for affected rows
            int R = selR;
            int rlo = R > 4 ? R - 4 : 0, rhi = R + 4 < AW ? R + 4 : AW - 1;
            if (tid <= rhi - rlo) {
                int r = rlo + tid;
                double mv = -2.0; int mc = 0x7fffffff;
                #pragma unroll
                for (int p = 0; p < 8; ++p) {
                    double v = bV[p * AW + r];
                    if (v > mv) { mv = v; mc = bC[p * AW + r]; }
                }
                rv[r] = mv; rcs[r] = mc;
            }
        }
        __syncthreads();
    }
}

// ---------------- kernel C: fused first-occurrence equality scans ----------------
__global__ __launch_bounds__(256) void kC(const float* __restrict__ hm,
                                          const int* __restrict__ rectR, const int* __restrict__ rectC,
                                          const float* __restrict__ maxv, int* __restrict__ scanres) {
    int b     = blockIdx.x & 31;
    int chunk = blockIdx.x >> 5;     // 0..31
    float mv[KK];
    int rr[5], rc[5], lim[KK];
    #pragma unroll
    for (int s = 0; s < KK; ++s) mv[s] = maxv[b * KK + s];
    #pragma unroll
    for (int t = 0; t < 5; ++t) { rr[t] = rectR[b * KK + t]; rc[t] = rectC[b * KK + t]; }
    int limmax = 0;
    #pragma unroll
    for (int s = 0; s < KK; ++s) {
        lim[s] = (rectR[b * KK + s] + 4) * H + rectC[b * KK + s] + 4;  // occurrence exists <= this
        limmax = lim[s] > limmax ? lim[s] : limmax;
    }
    const float4* h4 = (const float4*)(hm + b * HH);
    int local[KK];
    #pragma unroll
    for (int s = 0; s < KK; ++s) local[s] = 0x7fffffff;
    for (int i4 = chunk * 256 + threadIdx.x; i4 < NB4; i4 += 8192) {
        if (4 * i4 > limmax) break;          // ascending per-thread index: safe early-out
        float4 v = h4[i4];
        float vs[4] = {v.x, v.y, v.z, v.w};
        #pragma unroll
        for (int e = 0; e < 4; ++e) {
            #pragma unroll
            for (int s = 0; s < KK; ++s) {
                if (vs[e] == mv[s]) {
                    int n = 4 * i4 + e;
                    if (n <= lim[s]) {
                        int i = n / H, j = n - i * H;
                        bool masked = false;
                        for (int t = 0; t < s; ++t)
                            if ((unsigned)(i - rr[t]) < 5u && (unsigned)(j - rc[t]) < 5u) masked = true;
                        if (!masked && n < local[s]) local[s] = n;
                    }
                }
            }
        }
    }
    __shared__ int sm[KK];
    if (threadIdx.x < KK) sm[threadIdx.x] = 0x7fffffff;
    __syncthreads();
    #pragma unroll
    for (int s = 0; s < KK; ++s)
        if (local[s] != 0x7fffffff) atomicMin(&sm[s], local[s]);
    __syncthreads();
    if (threadIdx.x < KK && sm[threadIdx.x] != 0x7fffffff)
        atomicMin(&scanres[b * KK + threadIdx.x], sm[threadIdx.x]);
}

// ---------------- kernel D: refinement + round + confidences (768 thr, 2 waves/cluster) ----------------
__global__ __launch_bounds__(768) void kD(const float* __restrict__ hm,
                                          const int* __restrict__ scanres, float* __restrict__ out) {
    int b = blockIdx.x;
    const float* h = hm + b * HH;
    __shared__ float cly[2][KK], clx[2][KK];
    __shared__ float part[KK][2][3];
    if (threadIdx.x < KK) {
        int fh = scanres[b * KK + threadIdx.x];
        cly[0][threadIdx.x] = (float)(fh / H);
        clx[0][threadIdx.x] = (float)(fh % H);
    }
    __syncthreads();
    int wave = threadIdx.x >> 6, lane = threadIdx.x & 63;
    int k = wave >> 1, half = wave & 1;
    int cur = 0;
    for (int it = 0; it < 10; ++it) {
        float ys[KK], xs[KK];
        #pragma unroll
        for (int q = 0; q < KK; ++q) { ys[q] = cly[cur][q]; xs[q] = clx[cur][q]; }
        float cy = ys[k], cx = xs[k];
        int fy = (int)floorf(cy), fx = (int)floorf(cx);
        int i0 = fy - 12 > 0 ? fy - 12 : 0, i1 = fy + 13 < H - 1 ? fy + 13 : H - 1;
        int j0 = fx - 12 > 0 ? fx - 12 : 0, j1 = fx + 13 < H - 1 ? fx + 13 : H - 1;
        float sy = 0.0f, sx = 0.0f, sw = 0.0f;
        for (int idx = half * 64 + lane; idx < 676; idx += 128) {
            int di = idx / 26, dj = idx - di * 26;     // compile-time divisor
            int i = i0 + di, j = j0 + dj;
            if (i <= i1 && j <= j1) {
                float hv = h[i * H + j];               // issue early
                float fi = (float)i, fj = (float)j;
                float d2[KK];
                #pragma unroll
                for (int q = 0; q < KK; ++q) {
                    float dy = __fsub_rn(fi, ys[q]);
                    float dx = __fsub_rn(fj, xs[q]);
                    d2[q] = __fadd_rn(__fmul_rn(dy, dy), __fmul_rn(dx, dx));
                }
                if (d2[k] < 144.0f) {                  // == (d < 12), exact by monotonicity
                    float m2 = d2[0];
                    #pragma unroll
                    for (int q = 1; q < KK; ++q) m2 = fminf(m2, d2[q]);
                    float d = fmaxf(__fsqrt_rn(d2[k]), 0.001f);
                    float m = fmaxf(__fsqrt_rn(m2), 0.001f);
                    float w = __fmul_rn(__fdiv_rn(hv, d), __fdiv_rn(m, d));
                    sw += w;
                    sy += w * fi;
                    sx += w * fj;
                }
            }
        }
        #pragma unroll
        for (int off = 32; off; off >>= 1) {
            sy += __shfl_down(sy, (unsigned)off);
            sx += __shfl_down(sx, (unsigned)off);
            sw += __shfl_down(sw, (unsigned)off);
        }
        if (lane == 0) { part[k][half][0] = sy; part[k][half][1] = sx; part[k][half][2] = sw; }
        __syncthreads();
        if (threadIdx.x < KK) {
            int q = threadIdx.x;
            float ty = part[q][0][0] + part[q][1][0];
            float tx = part[q][0][1] + part[q][1][1];
            float tw = part[q][0][2] + part[q][1][2];
            cly[cur ^ 1][q] = ty / tw;
            clx[cur ^ 1][q] = tx / tw;
        }
        __syncthreads();
        cur ^= 1;
    }
    if (threadIdx.x < KK) {
        int q = threadIdx.x;
        int iy = __float2int_rn(cly[cur][q]);   // round-half-even, matches jnp.round
        int ix = __float2int_rn(clx[cur][q]);
        out[b * (KK * 2) + 2 * q]     = (float)iy;
        out[b * (KK * 2) + 2 * q + 1] = (float)ix;
        int s0 = iy - 2; if (s0 < 0) s0 = 0; if (s0 > H - 4) s0 = H - 4;   // clamped dynamic_slice
        int s1 = ix - 2; if (s1 < 0) s1 = 0; if (s1 > H - 4) s1 = H - 4;
        double cs = 0.0;
        for (int i = 0; i < 4; ++i)
            for (int j = 0; j < 4; ++j) cs += (double)h[(s0 + i) * H + (s1 + j)];
        out[BB * KK * 2 + b * KK + q] = (float)cs;
    }
}

// ---------------- launch ----------------
extern "C" void kernel_launch(void* const* d_in, const int* in_sizes, int n_in,
                              void* d_out, int out_size, void* d_ws, size_t ws_size,
                              hipStream_t stream) {
    const float* hm = (const float*)d_in[0];
    float* out = (float*)d_out;

    double* blockV  = (double*)d_ws;                 // 32*8*484 f64
    int*    blockC  = (int*)(blockV + BB * 8 * AW);  // 32*8*484 i32
    int*    rectR   = blockC + BB * 8 * AW;          // 32*6
    int*    rectC   = rectR + BB * KK;               // 32*6
    float*  maxv    = (float*)(rectC + BB * KK);     // 32*6
    int*    scanres = (int*)(maxv + BB * KK);        // 32*6

    kA<<<BB * 61, 512, 0, stream>>>(hm, blockV, blockC);
    kB<<<BB, 1024, 0, stream>>>(hm, blockV, blockC, rectR, rectC, maxv, scanres);
    kC<<<BB * 32, 256, 0, stream>>>(hm, rectR, rectC, maxv, scanres);
    kD<<<BB, 768, 0, stream>>>(hm, scanres, out);
}